// Round 17
// baseline (359.706 us; speedup 1.0000x reference)
//
#include <hip/hip_runtime.h>
#include <hip/hip_bf16.h>
#include <stdint.h>

// Problem constants
#define SEQ  2048
#define DIMM 1024
#define NH   16
#define DH   64
#define NB   4
#define MROWS (NB*SEQ)   // 8192
#define QKP  2080        // padded row stride for qk/vt (breaks 4KB aliasing)

typedef __attribute__((ext_vector_type(8))) short bf16x8;
typedef __attribute__((ext_vector_type(4))) float f32x4;
typedef __attribute__((ext_vector_type(16))) float f32x16;

#define LOG2E 1.44269504088896340736f

__device__ __forceinline__ unsigned short f2bf(float f) {
    union { float f; uint32_t u; } c; c.f = f;
    uint32_t r = c.u + 0x7fff + ((c.u >> 16) & 1);
    return (unsigned short)(r >> 16);
}

__device__ __forceinline__ void gload_lds16(const void* g, void* lds) {
    __builtin_amdgcn_global_load_lds(
        (const __attribute__((address_space(1))) unsigned int*)(g),
        (__attribute__((address_space(3))) unsigned int*)(lds),
        16, 0, 0);
}

// ---- fused prep: x fp32->bf16 convert + both weight transposes ------------
// blocks [0, 8192):            conv x -> x_bf (float4 / ushort4)
// blocks [8192, 8192+3072):    w_qkv [1024][3072] -> wqkvT [3072][1024]
// blocks [11264, 11264+1024):  w_out [1024][1024] -> woutT [1024][1024]
__global__ __launch_bounds__(256) void k_prep(const float* __restrict__ x,
                                              unsigned short* __restrict__ x_bf,
                                              const float* __restrict__ w_qkv,
                                              unsigned short* __restrict__ wqkvT,
                                              const float* __restrict__ w_out,
                                              unsigned short* __restrict__ woutT) {
    __shared__ unsigned short tile[32][33];
    const int bid = blockIdx.x;
    if (bid < 8192) {
        int i = bid * 256 + threadIdx.x;
        float4 v = ((const float4*)x)[i];
        ushort4 o;
        o.x = f2bf(v.x); o.y = f2bf(v.y); o.z = f2bf(v.z); o.w = f2bf(v.w);
        ((ushort4*)x_bf)[i] = o;
        return;
    }
    const float* W;
    unsigned short* Wt;
    int tn, tk, N;
    if (bid < 8192 + 3072) {
        W = w_qkv; Wt = wqkvT; N = 3072;
        tn = (bid - 8192) % 96; tk = (bid - 8192) / 96;
    } else {
        W = w_out; Wt = woutT; N = 1024;
        tn = (bid - 11264) % 32; tk = (bid - 11264) / 32;
    }
    const int K = 1024;
    int lx = threadIdx.x & 31, ly = threadIdx.x >> 5;  // 32 x 8
    #pragma unroll
    for (int i = 0; i < 32; i += 8) {
        int k = tk * 32 + ly + i;
        int n = tn * 32 + lx;
        tile[ly + i][lx] = f2bf(W[(size_t)k * N + n]);
    }
    __syncthreads();
    int k2 = tk * 32 + lx;
    #pragma unroll
    for (int i = 0; i < 32; i += 8) {
        int n2 = tn * 32 + ly + i;
        Wt[(size_t)n2 * K + k2] = tile[lx][ly + i];
    }
}

// --------- C[M][N] = A[M][K] * Bt[N][K]^T   (bf16 in) -----------------------
// BK=64 + row&7 XOR LDS swizzle (both-sides; verified R11).
// MODE 0: plain fp32 C (stride N_).
// MODE 1: fused QKV epilogue. Tiles tn<8: Q*0.125*log2e -> qk (stride QKP).
//         tn 8..15: K -> qk. tn>=16: V -> vt[bh][64][QKP] transposed.
template<int MODE>
__global__ __launch_bounds__(256) void k_gemm_bt(const unsigned short* __restrict__ A,
                                                 const unsigned short* __restrict__ Bt,
                                                 void* __restrict__ Cv,
                                                 unsigned short* __restrict__ vtv,
                                                 int M, int N_, int K) {
    constexpr int BM = 128, BN = 128, BK = 64;
    __shared__ unsigned short lA[BM * BK];
    __shared__ unsigned short lB[BN * BK];
    const int ntile = N_ / BN;
    const int tm = blockIdx.x / ntile;
    const int tn = blockIdx.x % ntile;
    const int t = threadIdx.x;
    const int w = t >> 6, l = t & 63;
    const int wr = w >> 1, wc = w & 1;

    const unsigned short* Abase = A + (size_t)tm * BM * K;
    const unsigned short* Bbase = Bt + (size_t)tn * BN * K;

    f32x4 acc[4][4] = {};

    const int rswz = (l & 7) << 4;

    for (int k0 = 0; k0 < K; k0 += BK) {
        __syncthreads();
        #pragma unroll
        for (int i = 0; i < 4; ++i) {
            const int o  = i * 4096 + t * 16;
            const int so = o ^ (((o >> 7) & 7) << 4);
            const int row = so >> 7;
            const int kb  = so & 127;
            gload_lds16((const char*)(Abase + (size_t)row * K + k0) + kb,
                        (char*)lA + i * 4096 + w * 1024);
            gload_lds16((const char*)(Bbase + (size_t)row * K + k0) + kb,
                        (char*)lB + i * 4096 + w * 1024);
        }
        __syncthreads();

        #pragma unroll
        for (int kk = 0; kk < 2; ++kk) {
            bf16x8 af[4], bfv[4];
            #pragma unroll
            for (int i = 0; i < 4; ++i) {
                const int ea = ((wr * 64 + i * 16 + (l & 15)) << 7) + kk * 64 + ((l >> 4) << 4);
                af[i] = *(const bf16x8*)((const char*)lA + (ea ^ rswz));
            }
            #pragma unroll
            for (int j = 0; j < 4; ++j) {
                const int eb = ((wc * 64 + j * 16 + (l & 15)) << 7) + kk * 64 + ((l >> 4) << 4);
                bfv[j] = *(const bf16x8*)((const char*)lB + (eb ^ rswz));
            }
            #pragma unroll
            for (int i = 0; i < 4; ++i)
                #pragma unroll
                for (int j = 0; j < 4; ++j)
                    acc[i][j] = __builtin_amdgcn_mfma_f32_16x16x32_bf16(af[i], bfv[j], acc[i][j], 0, 0, 0);
        }
    }

    const int row0 = tm * BM + wr * 64 + (l >> 4) * 4;
    const int col0 = tn * BN + wc * 64 + (l & 15);

    if (MODE == 0) {
        float* Cf = (float*)Cv;
        #pragma unroll
        for (int i = 0; i < 4; ++i)
            #pragma unroll
            for (int j = 0; j < 4; ++j)
                #pragma unroll
                for (int r = 0; r < 4; ++r)
                    Cf[(size_t)(row0 + i * 16 + r) * N_ + (col0 + j * 16)] = acc[i][j][r];
    } else if (tn < 16) {
        const float cs = (tn < 8) ? 0.125f * LOG2E : 1.0f;
        unsigned short* qk = (unsigned short*)Cv;
        #pragma unroll
        for (int i = 0; i < 4; ++i)
            #pragma unroll
            for (int j = 0; j < 4; ++j)
                #pragma unroll
                for (int r = 0; r < 4; ++r)
                    qk[(size_t)(row0 + i * 16 + r) * QKP + (col0 + j * 16)] = f2bf(acc[i][j][r] * cs);
    } else {
        #pragma unroll
        for (int i = 0; i < 4; ++i) {
            const int rbase = row0 + i * 16;
            const int bq = rbase >> 11;
            const int n0 = rbase & 2047;
            #pragma unroll
            for (int j = 0; j < 4; ++j) {
                const int c = col0 + j * 16 - 2048;
                const int hh = c >> 6, dd = c & 63;
                uint2 u;
                u.x = (unsigned int)f2bf(acc[i][j][0]) | ((unsigned int)f2bf(acc[i][j][1]) << 16);
                u.y = (unsigned int)f2bf(acc[i][j][2]) | ((unsigned int)f2bf(acc[i][j][3]) << 16);
                *(uint2*)(vtv + ((size_t)(bq * 16 + hh) * 64 + dd) * QKP + n0) = u;
            }
        }
    }
}

// -- causal flash attention (v17: R16 body, UN-PAIRED 1-wave blocks) ---------
// 4096 blocks x 64 thr: block = (bh, 32-q-row chunk c32). At 112 VGPR the HW
// tier holds 16 waves/CU; the old paired grid supplied only 8 -> supply-limited.
// Heavy-first ordering (c32 = 63 - bid>>6) + 4096-block oversubscription
// replaces explicit pairing for balance. Body identical to R16.
__global__ __launch_bounds__(64, 4) void k_attn17(const unsigned short* __restrict__ qk,
                                                  const unsigned short* __restrict__ vt,
                                                  unsigned short* __restrict__ out) {
    const int bid = blockIdx.x;               // 4096
    const int bh = bid & 63;                  // same-bh blocks stride-8 -> XCD-local
    const int c32 = 63 - (bid >> 6);          // heavy chunks first
    const int b = bh >> 4, h = bh & 15;
    const int l = threadIdx.x;                // 0..63
    const int l31 = l & 31, hi = l >> 5;

    const unsigned short* qp = qk + (size_t)(b * SEQ) * QKP + h * 64;   // Q cols
    unsigned short* op = out + (size_t)(b * SEQ) * DIMM + h * 64;

    constexpr int KSTEP = 64 * QKP * 2;       // 64 kv rows in qk (bytes)
    constexpr int VSTEP = 64 * 2;             // 64 kv cols in vt (bytes)

    union U8 { uint32_t u[4]; bf16x8 v; };

    const int q0w = c32 * 32;                 // wave's first q row
    const int qrow = q0w + l31;               // this lane's q row
    const int nt = (q0w >> 6) + 1;            // kv-tile trip count

    // Q as B-operand: col = l31 (q), k = m*16 + hi*8 + e (prescaled 1/8*log2e)
    bf16x8 qf[4];
    #pragma unroll
    for (int m = 0; m < 4; ++m)
        qf[m] = *(const bf16x8*)(qp + (size_t)(q0w + l31) * QKP + m * 16 + hi * 8);

    // O^T accumulators: rows d = crow(r,hi) / 32+crow, col q = l31 (own lane)
    f32x16 accO0 = {}, accO1 = {};
    float m_run = -INFINITY, l_run = 0.f;

    // incremental byte pointers (K rows kv = {0,32}+l31; V^T rows d = {0,32}+l31)
    const char* kp0 = (const char*)(qk + ((size_t)b * SEQ + l31) * QKP + 1024 + h * 64 + hi * 8);
    const char* kp1 = kp0 + 32 * QKP * 2;
    const char* vp0 = (const char*)(vt + ((size_t)bh * 64 + l31) * QKP + hi * 8);
    const char* vp1 = vp0 + 32 * QKP * 2;

    // K tile 0 into registers; pointers advance to tile 1
    bf16x8 kf[2][4];
    #pragma unroll
    for (int m = 0; m < 4; ++m) {
        kf[0][m] = *(const bf16x8*)(kp0 + m * 32);
        kf[1][m] = *(const bf16x8*)(kp1 + m * 32);
    }
    kp0 += KSTEP; kp1 += KSTEP;

    for (int kt = 0; kt < nt; ++kt) {
        const int kv0 = kt * 64;
        const bool msk = (kt == nt - 1);

        // QK^T swapped -> S^T: lane holds q=l31, kv = f*32 + crow(r,hi)
        f32x16 s0 = {}, s1 = {};
        __builtin_amdgcn_s_setprio(1);
        #pragma unroll
        for (int m = 0; m < 4; ++m) {
            s0 = __builtin_amdgcn_mfma_f32_32x32x16_bf16(kf[0][m], qf[m], s0, 0, 0, 0);
            s1 = __builtin_amdgcn_mfma_f32_32x32x16_bf16(kf[1][m], qf[m], s1, 0, 0, 0);
        }
        __builtin_amdgcn_s_setprio(0);

        // V^T fragments for current tile (imm offsets), issued early
        bf16x8 vf0[4], vf1[4];
        #pragma unroll
        for (int m = 0; m < 4; ++m) {
            vf0[m] = *(const bf16x8*)(vp0 + m * 32);
            vf1[m] = *(const bf16x8*)(vp1 + m * 32);
        }
        vp0 += VSTEP; vp1 += VSTEP;

        // K prefetch for next tile (unconditional; overrun is valid ws)
        #pragma unroll
        for (int m = 0; m < 4; ++m) {
            kf[0][m] = *(const bf16x8*)(kp0 + m * 32);
            kf[1][m] = *(const bf16x8*)(kp1 + m * 32);
        }
        kp0 += KSTEP; kp1 += KSTEP;

        // ---- in-lane online softmax, exp2 domain, T13 defer-max ----
        float tmax = -1e30f;
        #pragma unroll
        for (int r = 0; r < 16; ++r) {
            const int crow = (r & 3) + 8 * (r >> 2) + 4 * hi;
            float v0 = s0[r];
            float v1 = s1[r];
            if (msk) {
                if (kv0 + crow > qrow)      v0 = -1e30f;
                if (kv0 + 32 + crow > qrow) v1 = -1e30f;
            }
            s0[r] = v0; s1[r] = v1;
            tmax = fmaxf(tmax, fmaxf(v0, v1));
        }
        tmax = fmaxf(tmax, __shfl_xor(tmax, 32));      // other kv half
        const bool defer = __all(tmax <= m_run + 8.0f);  // P bounded by 2^8
        float fct = 1.0f;
        if (!defer) {
            const float mnew = fmaxf(m_run, tmax);
            fct = exp2f(m_run - mnew);
            m_run = mnew;
            #pragma unroll
            for (int r = 0; r < 16; ++r) { accO0[r] *= fct; accO1[r] *= fct; }
        }
        float ps = 0.f;
        #pragma unroll
        for (int r = 0; r < 16; ++r) {
            float p0 = exp2f(s0[r] - m_run);
            float p1 = exp2f(s1[r] - m_run);
            s0[r] = p0; s1[r] = p1;
            ps += p0 + p1;
        }
        ps += __shfl_xor(ps, 32);
        l_run = l_run * fct + ps;

        // ---- P -> bf16 pack + permlane redistribution + PV (O^T) ----
        uint32_t pw0[8], pw1[8];
        #pragma unroll
        for (int i = 0; i < 8; ++i) {
            asm("v_cvt_pk_bf16_f32 %0, %1, %2" : "=v"(pw0[i]) : "v"(s0[2*i]), "v"(s0[2*i+1]));
            asm("v_cvt_pk_bf16_f32 %0, %1, %2" : "=v"(pw1[i]) : "v"(s1[2*i]), "v"(s1[2*i+1]));
        }
        __builtin_amdgcn_s_setprio(1);
        #define PVCHUNK(PW, BASE, VF0, VF1) do {                                     \
            uint32_t a0 = PW[BASE+0], b0 = PW[BASE+2];                               \
            uint32_t a1 = PW[BASE+1], b1 = PW[BASE+3];                               \
            asm("v_permlane32_swap_b32 %0, %1" : "+v"(a0), "+v"(b0));                \
            asm("v_permlane32_swap_b32 %0, %1" : "+v"(a1), "+v"(b1));                \
            U8 pb; pb.u[0] = a0; pb.u[1] = a1; pb.u[2] = b0; pb.u[3] = b1;           \
            accO0 = __builtin_amdgcn_mfma_f32_32x32x16_bf16(VF0, pb.v, accO0, 0, 0, 0); \
            accO1 = __builtin_amdgcn_mfma_f32_32x32x16_bf16(VF1, pb.v, accO1, 0, 0, 0); \
        } while (0)
        PVCHUNK(pw0, 0, vf0[0], vf1[0]);
        PVCHUNK(pw0, 4, vf0[1], vf1[1]);
        PVCHUNK(pw1, 0, vf0[2], vf1[2]);
        PVCHUNK(pw1, 4, vf0[3], vf1[3]);
        #undef PVCHUNK
        __builtin_amdgcn_s_setprio(0);
    }

    // epilogue: lane holds O[q = q0w+l31][d = crow + {0,32}], own l_run.
    const float inv = 1.0f / l_run;
    unsigned short* orow = op + (size_t)(q0w + l31) * DIMM;
    #pragma unroll
    for (int g = 0; g < 4; ++g) {
        uint2 u0, u1;
        float a0 = accO0[4*g+0] * inv, a1 = accO0[4*g+1] * inv;
        float a2 = accO0[4*g+2] * inv, a3 = accO0[4*g+3] * inv;
        float c0 = accO1[4*g+0] * inv, c1 = accO1[4*g+1] * inv;
        float c2 = accO1[4*g+2] * inv, c3 = accO1[4*g+3] * inv;
        asm("v_cvt_pk_bf16_f32 %0, %1, %2" : "=v"(u0.x) : "v"(a0), "v"(a1));
        asm("v_cvt_pk_bf16_f32 %0, %1, %2" : "=v"(u0.y) : "v"(a2), "v"(a3));
        asm("v_cvt_pk_bf16_f32 %0, %1, %2" : "=v"(u1.x) : "v"(c0), "v"(c1));
        asm("v_cvt_pk_bf16_f32 %0, %1, %2" : "=v"(u1.y) : "v"(c2), "v"(c3));
        *(uint2*)(orow + 8*g + 4*hi)      = u0;   // d = 8g+4hi .. +3
        *(uint2*)(orow + 32 + 8*g + 4*hi) = u1;   // d = 32+8g+4hi .. +3
    }
}

// ---------------------------------------------------------------------------
extern "C" void kernel_launch(void* const* d_in, const int* in_sizes, int n_in,
                              void* d_out, int out_size, void* d_ws, size_t ws_size,
                              hipStream_t stream) {
    const float* x     = (const float*)d_in[0];   // [4,2048,1024]
    const float* w_qkv = (const float*)d_in[1];   // [1024,3072]
    const float* w_out = (const float*)d_in[2];   // [1024,1024]

    unsigned short* x_bf   = (unsigned short*)d_ws;
    unsigned short* wqkvT  = x_bf   + (size_t)MROWS * DIMM;
    unsigned short* woutT  = wqkvT  + (size_t)3 * DIMM * DIMM;
    unsigned short* qk_buf = woutT  + (size_t)DIMM * DIMM;           // [8192][QKP]
    unsigned short* vt     = qk_buf + (size_t)MROWS * QKP;           // [64][64][QKP]
    unsigned short* aout   = vt     + (size_t)64 * DH * QKP;         // [8192][1024]

    // 1. fused prep: conv + both weight transposes in one dispatch
    k_prep<<<8192 + 3072 + 1024, 256, 0, stream>>>(x, x_bf, w_qkv, wqkvT, w_out, woutT);

    // 2. QKV projection, fused epilogue: Q(scaled)|K -> qk_buf, V^T -> vt
    k_gemm_bt<1><<<(MROWS / 128) * (3 * DIMM / 128), 256, 0, stream>>>(
        x_bf, wqkvT, qk_buf, vt, MROWS, 3 * DIMM, DIMM);

    // 3. causal flash attention (un-paired 1-wave blocks, 16 waves/CU supply)
    k_attn17<<<4096, 64, 0, stream>>>(qk_buf, vt, aout);

    // 4. output projection: [8192,1024] x [1024,1024] -> fp32 d_out
    k_gemm_bt<0><<<(MROWS / 128) * (DIMM / 128), 256, 0, stream>>>(
        aout, woutT, d_out, nullptr, MROWS, DIMM, DIMM);
}

// Round 18
// 199.347 us; speedup vs baseline: 1.8044x; 1.8044x over previous
//
#include <hip/hip_runtime.h>
#include <hip/hip_bf16.h>
#include <stdint.h>

// Problem constants
#define SEQ  2048
#define DIMM 1024
#define NH   16
#define DH   64
#define NB   4
#define MROWS (NB*SEQ)   // 8192
#define QKP  2080        // padded row stride for qk/vt (breaks 4KB aliasing)

typedef __attribute__((ext_vector_type(8))) short bf16x8;
typedef __attribute__((ext_vector_type(4))) float f32x4;
typedef __attribute__((ext_vector_type(16))) float f32x16;

#define LOG2E 1.44269504088896340736f

__device__ __forceinline__ unsigned short f2bf(float f) {
    union { float f; uint32_t u; } c; c.f = f;
    uint32_t r = c.u + 0x7fff + ((c.u >> 16) & 1);
    return (unsigned short)(r >> 16);
}

__device__ __forceinline__ void gload_lds16(const void* g, void* lds) {
    __builtin_amdgcn_global_load_lds(
        (const __attribute__((address_space(1))) unsigned int*)(g),
        (__attribute__((address_space(3))) unsigned int*)(lds),
        16, 0, 0);
}

// ---- fused prep: x fp32->bf16 convert + both weight transposes ------------
// blocks [0, 8192):            conv x -> x_bf (float4 / ushort4)
// blocks [8192, 8192+3072):    w_qkv [1024][3072] -> wqkvT [3072][1024]
// blocks [11264, 11264+1024):  w_out [1024][1024] -> woutT [1024][1024]
__global__ __launch_bounds__(256) void k_prep(const float* __restrict__ x,
                                              unsigned short* __restrict__ x_bf,
                                              const float* __restrict__ w_qkv,
                                              unsigned short* __restrict__ wqkvT,
                                              const float* __restrict__ w_out,
                                              unsigned short* __restrict__ woutT) {
    __shared__ unsigned short tile[32][33];
    const int bid = blockIdx.x;
    if (bid < 8192) {
        int i = bid * 256 + threadIdx.x;
        float4 v = ((const float4*)x)[i];
        ushort4 o;
        o.x = f2bf(v.x); o.y = f2bf(v.y); o.z = f2bf(v.z); o.w = f2bf(v.w);
        ((ushort4*)x_bf)[i] = o;
        return;
    }
    const float* W;
    unsigned short* Wt;
    int tn, tk, N;
    if (bid < 8192 + 3072) {
        W = w_qkv; Wt = wqkvT; N = 3072;
        tn = (bid - 8192) % 96; tk = (bid - 8192) / 96;
    } else {
        W = w_out; Wt = woutT; N = 1024;
        tn = (bid - 11264) % 32; tk = (bid - 11264) / 32;
    }
    const int K = 1024;
    int lx = threadIdx.x & 31, ly = threadIdx.x >> 5;  // 32 x 8
    #pragma unroll
    for (int i = 0; i < 32; i += 8) {
        int k = tk * 32 + ly + i;
        int n = tn * 32 + lx;
        tile[ly + i][lx] = f2bf(W[(size_t)k * N + n]);
    }
    __syncthreads();
    int k2 = tk * 32 + lx;
    #pragma unroll
    for (int i = 0; i < 32; i += 8) {
        int n2 = tn * 32 + ly + i;
        Wt[(size_t)n2 * K + k2] = tile[lx][ly + i];
    }
}

// --------- C[M][N] = A[M][K] * Bt[N][K]^T   (bf16 in) -----------------------
// BK=64 + row&7 XOR LDS swizzle (both-sides; verified R11).
// MODE 0: plain fp32 C (stride N_).
// MODE 1: fused QKV epilogue. Tiles tn<8: Q*0.125*log2e -> qk (stride QKP).
//         tn 8..15: K -> qk. tn>=16: V -> vt[bh][64][QKP] transposed.
template<int MODE>
__global__ __launch_bounds__(256) void k_gemm_bt(const unsigned short* __restrict__ A,
                                                 const unsigned short* __restrict__ Bt,
                                                 void* __restrict__ Cv,
                                                 unsigned short* __restrict__ vtv,
                                                 int M, int N_, int K) {
    constexpr int BM = 128, BN = 128, BK = 64;
    __shared__ unsigned short lA[BM * BK];
    __shared__ unsigned short lB[BN * BK];
    const int ntile = N_ / BN;
    const int tm = blockIdx.x / ntile;
    const int tn = blockIdx.x % ntile;
    const int t = threadIdx.x;
    const int w = t >> 6, l = t & 63;
    const int wr = w >> 1, wc = w & 1;

    const unsigned short* Abase = A + (size_t)tm * BM * K;
    const unsigned short* Bbase = Bt + (size_t)tn * BN * K;

    f32x4 acc[4][4] = {};

    const int rswz = (l & 7) << 4;

    for (int k0 = 0; k0 < K; k0 += BK) {
        __syncthreads();
        #pragma unroll
        for (int i = 0; i < 4; ++i) {
            const int o  = i * 4096 + t * 16;
            const int so = o ^ (((o >> 7) & 7) << 4);
            const int row = so >> 7;
            const int kb  = so & 127;
            gload_lds16((const char*)(Abase + (size_t)row * K + k0) + kb,
                        (char*)lA + i * 4096 + w * 1024);
            gload_lds16((const char*)(Bbase + (size_t)row * K + k0) + kb,
                        (char*)lB + i * 4096 + w * 1024);
        }
        __syncthreads();

        #pragma unroll
        for (int kk = 0; kk < 2; ++kk) {
            bf16x8 af[4], bfv[4];
            #pragma unroll
            for (int i = 0; i < 4; ++i) {
                const int ea = ((wr * 64 + i * 16 + (l & 15)) << 7) + kk * 64 + ((l >> 4) << 4);
                af[i] = *(const bf16x8*)((const char*)lA + (ea ^ rswz));
            }
            #pragma unroll
            for (int j = 0; j < 4; ++j) {
                const int eb = ((wc * 64 + j * 16 + (l & 15)) << 7) + kk * 64 + ((l >> 4) << 4);
                bfv[j] = *(const bf16x8*)((const char*)lB + (eb ^ rswz));
            }
            #pragma unroll
            for (int i = 0; i < 4; ++i)
                #pragma unroll
                for (int j = 0; j < 4; ++j)
                    acc[i][j] = __builtin_amdgcn_mfma_f32_16x16x32_bf16(af[i], bfv[j], acc[i][j], 0, 0, 0);
        }
    }

    const int row0 = tm * BM + wr * 64 + (l >> 4) * 4;
    const int col0 = tn * BN + wc * 64 + (l & 15);

    if (MODE == 0) {
        float* Cf = (float*)Cv;
        #pragma unroll
        for (int i = 0; i < 4; ++i)
            #pragma unroll
            for (int j = 0; j < 4; ++j)
                #pragma unroll
                for (int r = 0; r < 4; ++r)
                    Cf[(size_t)(row0 + i * 16 + r) * N_ + (col0 + j * 16)] = acc[i][j][r];
    } else if (tn < 16) {
        const float cs = (tn < 8) ? 0.125f * LOG2E : 1.0f;
        unsigned short* qk = (unsigned short*)Cv;
        #pragma unroll
        for (int i = 0; i < 4; ++i)
            #pragma unroll
            for (int j = 0; j < 4; ++j)
                #pragma unroll
                for (int r = 0; r < 4; ++r)
                    qk[(size_t)(row0 + i * 16 + r) * QKP + (col0 + j * 16)] = f2bf(acc[i][j][r] * cs);
    } else {
        #pragma unroll
        for (int i = 0; i < 4; ++i) {
            const int rbase = row0 + i * 16;
            const int bq = rbase >> 11;
            const int n0 = rbase & 2047;
            #pragma unroll
            for (int j = 0; j < 4; ++j) {
                const int c = col0 + j * 16 - 2048;
                const int hh = c >> 6, dd = c & 63;
                uint2 u;
                u.x = (unsigned int)f2bf(acc[i][j][0]) | ((unsigned int)f2bf(acc[i][j][1]) << 16);
                u.y = (unsigned int)f2bf(acc[i][j][2]) | ((unsigned int)f2bf(acc[i][j][3]) << 16);
                *(uint2*)(vtv + ((size_t)(bq * 16 + hh) * 64 + dd) * QKP + n0) = u;
            }
        }
    }
}

// -- causal flash attention (v18: un-paired 1-wave blocks, VGPR cap fixed) ---
// 4096 blocks x 64 thr. __launch_bounds__(64,2) -> VGPR cap 128 (law: 256/arg),
// holds the 112-live body with NO spills; HW tier at 112 VGPR = 16 waves/CU,
// grid supplies 16 blocks/CU. Heavy-first ordering; stride-8 bh -> XCD-local.
__global__ __launch_bounds__(64, 2) void k_attn18(const unsigned short* __restrict__ qk,
                                                  const unsigned short* __restrict__ vt,
                                                  unsigned short* __restrict__ out) {
    const int bid = blockIdx.x;               // 4096
    const int bh = bid & 63;                  // same-bh blocks stride-8 -> XCD-local
    const int c32 = 63 - (bid >> 6);          // heavy chunks first
    const int b = bh >> 4, h = bh & 15;
    const int l = threadIdx.x;                // 0..63
    const int l31 = l & 31, hi = l >> 5;

    const unsigned short* qp = qk + (size_t)(b * SEQ) * QKP + h * 64;   // Q cols
    unsigned short* op = out + (size_t)(b * SEQ) * DIMM + h * 64;

    constexpr int KSTEP = 64 * QKP * 2;       // 64 kv rows in qk (bytes)
    constexpr int VSTEP = 64 * 2;             // 64 kv cols in vt (bytes)

    union U8 { uint32_t u[4]; bf16x8 v; };

    const int q0w = c32 * 32;                 // wave's first q row
    const int qrow = q0w + l31;               // this lane's q row
    const int nt = (q0w >> 6) + 1;            // kv-tile trip count

    // Q as B-operand: col = l31 (q), k = m*16 + hi*8 + e (prescaled 1/8*log2e)
    bf16x8 qf[4];
    #pragma unroll
    for (int m = 0; m < 4; ++m)
        qf[m] = *(const bf16x8*)(qp + (size_t)(q0w + l31) * QKP + m * 16 + hi * 8);

    // O^T accumulators: rows d = crow(r,hi) / 32+crow, col q = l31 (own lane)
    f32x16 accO0 = {}, accO1 = {};
    float m_run = -INFINITY, l_run = 0.f;

    // incremental byte pointers (K rows kv = {0,32}+l31; V^T rows d = {0,32}+l31)
    const char* kp0 = (const char*)(qk + ((size_t)b * SEQ + l31) * QKP + 1024 + h * 64 + hi * 8);
    const char* kp1 = kp0 + 32 * QKP * 2;
    const char* vp0 = (const char*)(vt + ((size_t)bh * 64 + l31) * QKP + hi * 8);
    const char* vp1 = vp0 + 32 * QKP * 2;

    // K tile 0 into registers; pointers advance to tile 1
    bf16x8 kf[2][4];
    #pragma unroll
    for (int m = 0; m < 4; ++m) {
        kf[0][m] = *(const bf16x8*)(kp0 + m * 32);
        kf[1][m] = *(const bf16x8*)(kp1 + m * 32);
    }
    kp0 += KSTEP; kp1 += KSTEP;

    for (int kt = 0; kt < nt; ++kt) {
        const int kv0 = kt * 64;
        const bool msk = (kt == nt - 1);

        // QK^T swapped -> S^T: lane holds q=l31, kv = f*32 + crow(r,hi)
        f32x16 s0 = {}, s1 = {};
        __builtin_amdgcn_s_setprio(1);
        #pragma unroll
        for (int m = 0; m < 4; ++m) {
            s0 = __builtin_amdgcn_mfma_f32_32x32x16_bf16(kf[0][m], qf[m], s0, 0, 0, 0);
            s1 = __builtin_amdgcn_mfma_f32_32x32x16_bf16(kf[1][m], qf[m], s1, 0, 0, 0);
        }
        __builtin_amdgcn_s_setprio(0);

        // V^T fragments for current tile (imm offsets), issued early
        bf16x8 vf0[4], vf1[4];
        #pragma unroll
        for (int m = 0; m < 4; ++m) {
            vf0[m] = *(const bf16x8*)(vp0 + m * 32);
            vf1[m] = *(const bf16x8*)(vp1 + m * 32);
        }
        vp0 += VSTEP; vp1 += VSTEP;

        // K prefetch for next tile (unconditional; overrun is valid ws)
        #pragma unroll
        for (int m = 0; m < 4; ++m) {
            kf[0][m] = *(const bf16x8*)(kp0 + m * 32);
            kf[1][m] = *(const bf16x8*)(kp1 + m * 32);
        }
        kp0 += KSTEP; kp1 += KSTEP;

        // ---- in-lane online softmax, exp2 domain, T13 defer-max ----
        float tmax = -1e30f;
        #pragma unroll
        for (int r = 0; r < 16; ++r) {
            const int crow = (r & 3) + 8 * (r >> 2) + 4 * hi;
            float v0 = s0[r];
            float v1 = s1[r];
            if (msk) {
                if (kv0 + crow > qrow)      v0 = -1e30f;
                if (kv0 + 32 + crow > qrow) v1 = -1e30f;
            }
            s0[r] = v0; s1[r] = v1;
            tmax = fmaxf(tmax, fmaxf(v0, v1));
        }
        tmax = fmaxf(tmax, __shfl_xor(tmax, 32));      // other kv half
        const bool defer = __all(tmax <= m_run + 8.0f);  // P bounded by 2^8
        float fct = 1.0f;
        if (!defer) {
            const float mnew = fmaxf(m_run, tmax);
            fct = exp2f(m_run - mnew);
            m_run = mnew;
            #pragma unroll
            for (int r = 0; r < 16; ++r) { accO0[r] *= fct; accO1[r] *= fct; }
        }
        float ps = 0.f;
        #pragma unroll
        for (int r = 0; r < 16; ++r) {
            float p0 = exp2f(s0[r] - m_run);
            float p1 = exp2f(s1[r] - m_run);
            s0[r] = p0; s1[r] = p1;
            ps += p0 + p1;
        }
        ps += __shfl_xor(ps, 32);
        l_run = l_run * fct + ps;

        // ---- P -> bf16 pack + permlane redistribution + PV (O^T) ----
        uint32_t pw0[8], pw1[8];
        #pragma unroll
        for (int i = 0; i < 8; ++i) {
            asm("v_cvt_pk_bf16_f32 %0, %1, %2" : "=v"(pw0[i]) : "v"(s0[2*i]), "v"(s0[2*i+1]));
            asm("v_cvt_pk_bf16_f32 %0, %1, %2" : "=v"(pw1[i]) : "v"(s1[2*i]), "v"(s1[2*i+1]));
        }
        __builtin_amdgcn_s_setprio(1);
        #define PVCHUNK(PW, BASE, VF0, VF1) do {                                     \
            uint32_t a0 = PW[BASE+0], b0 = PW[BASE+2];                               \
            uint32_t a1 = PW[BASE+1], b1 = PW[BASE+3];                               \
            asm("v_permlane32_swap_b32 %0, %1" : "+v"(a0), "+v"(b0));                \
            asm("v_permlane32_swap_b32 %0, %1" : "+v"(a1), "+v"(b1));                \
            U8 pb; pb.u[0] = a0; pb.u[1] = a1; pb.u[2] = b0; pb.u[3] = b1;           \
            accO0 = __builtin_amdgcn_mfma_f32_32x32x16_bf16(VF0, pb.v, accO0, 0, 0, 0); \
            accO1 = __builtin_amdgcn_mfma_f32_32x32x16_bf16(VF1, pb.v, accO1, 0, 0, 0); \
        } while (0)
        PVCHUNK(pw0, 0, vf0[0], vf1[0]);
        PVCHUNK(pw0, 4, vf0[1], vf1[1]);
        PVCHUNK(pw1, 0, vf0[2], vf1[2]);
        PVCHUNK(pw1, 4, vf0[3], vf1[3]);
        #undef PVCHUNK
        __builtin_amdgcn_s_setprio(0);
    }

    // epilogue: lane holds O[q = q0w+l31][d = crow + {0,32}], own l_run.
    const float inv = 1.0f / l_run;
    unsigned short* orow = op + (size_t)(q0w + l31) * DIMM;
    #pragma unroll
    for (int g = 0; g < 4; ++g) {
        uint2 u0, u1;
        float a0 = accO0[4*g+0] * inv, a1 = accO0[4*g+1] * inv;
        float a2 = accO0[4*g+2] * inv, a3 = accO0[4*g+3] * inv;
        float c0 = accO1[4*g+0] * inv, c1 = accO1[4*g+1] * inv;
        float c2 = accO1[4*g+2] * inv, c3 = accO1[4*g+3] * inv;
        asm("v_cvt_pk_bf16_f32 %0, %1, %2" : "=v"(u0.x) : "v"(a0), "v"(a1));
        asm("v_cvt_pk_bf16_f32 %0, %1, %2" : "=v"(u0.y) : "v"(a2), "v"(a3));
        asm("v_cvt_pk_bf16_f32 %0, %1, %2" : "=v"(u1.x) : "v"(c0), "v"(c1));
        asm("v_cvt_pk_bf16_f32 %0, %1, %2" : "=v"(u1.y) : "v"(c2), "v"(c3));
        *(uint2*)(orow + 8*g + 4*hi)      = u0;   // d = 8g+4hi .. +3
        *(uint2*)(orow + 32 + 8*g + 4*hi) = u1;   // d = 32+8g+4hi .. +3
    }
}

// ---------------------------------------------------------------------------
extern "C" void kernel_launch(void* const* d_in, const int* in_sizes, int n_in,
                              void* d_out, int out_size, void* d_ws, size_t ws_size,
                              hipStream_t stream) {
    const float* x     = (const float*)d_in[0];   // [4,2048,1024]
    const float* w_qkv = (const float*)d_in[1];   // [1024,3072]
    const float* w_out = (const float*)d_in[2];   // [1024,1024]

    unsigned short* x_bf   = (unsigned short*)d_ws;
    unsigned short* wqkvT  = x_bf   + (size_t)MROWS * DIMM;
    unsigned short* woutT  = wqkvT  + (size_t)3 * DIMM * DIMM;
    unsigned short* qk_buf = woutT  + (size_t)DIMM * DIMM;           // [8192][QKP]
    unsigned short* vt     = qk_buf + (size_t)MROWS * QKP;           // [64][64][QKP]
    unsigned short* aout   = vt     + (size_t)64 * DH * QKP;         // [8192][1024]

    // 1. fused prep: conv + both weight transposes in one dispatch
    k_prep<<<8192 + 3072 + 1024, 256, 0, stream>>>(x, x_bf, w_qkv, wqkvT, w_out, woutT);

    // 2. QKV projection, fused epilogue: Q(scaled)|K -> qk_buf, V^T -> vt
    k_gemm_bt<1><<<(MROWS / 128) * (3 * DIMM / 128), 256, 0, stream>>>(
        x_bf, wqkvT, qk_buf, vt, MROWS, 3 * DIMM, DIMM);

    // 3. causal flash attention (un-paired 1-wave blocks, cap-128 bounds)
    k_attn18<<<4096, 64, 0, stream>>>(qk_buf, vt, aout);

    // 4. output projection: [8192,1024] x [1024,1024] -> fp32 d_out
    k_gemm_bt<0><<<(MROWS / 128) * (DIMM / 128), 256, 0, stream>>>(
        aout, woutT, d_out, nullptr, MROWS, DIMM, DIMM);
}

// Round 19
// 199.102 us; speedup vs baseline: 1.8066x; 1.0012x over previous
//
#include <hip/hip_runtime.h>
#include <hip/hip_bf16.h>
#include <stdint.h>

// Problem constants
#define SEQ  2048
#define DIMM 1024
#define NH   16
#define DH   64
#define NB   4
#define MROWS (NB*SEQ)   // 8192
#define QKP  2080        // padded row stride for qk/vt (breaks 4KB aliasing)

typedef __attribute__((ext_vector_type(8))) short bf16x8;
typedef __attribute__((ext_vector_type(4))) float f32x4;
typedef __attribute__((ext_vector_type(16))) float f32x16;

#define LOG2E 1.44269504088896340736f

template<bool B> struct BoolC { static constexpr bool value = B; };

__device__ __forceinline__ unsigned short f2bf(float f) {
    union { float f; uint32_t u; } c; c.f = f;
    uint32_t r = c.u + 0x7fff + ((c.u >> 16) & 1);
    return (unsigned short)(r >> 16);
}

__device__ __forceinline__ void gload_lds16(const void* g, void* lds) {
    __builtin_amdgcn_global_load_lds(
        (const __attribute__((address_space(1))) unsigned int*)(g),
        (__attribute__((address_space(3))) unsigned int*)(lds),
        16, 0, 0);
}

// ---- fused prep: x fp32->bf16 convert + both weight transposes ------------
__global__ __launch_bounds__(256) void k_prep(const float* __restrict__ x,
                                              unsigned short* __restrict__ x_bf,
                                              const float* __restrict__ w_qkv,
                                              unsigned short* __restrict__ wqkvT,
                                              const float* __restrict__ w_out,
                                              unsigned short* __restrict__ woutT) {
    __shared__ unsigned short tile[32][33];
    const int bid = blockIdx.x;
    if (bid < 8192) {
        int i = bid * 256 + threadIdx.x;
        float4 v = ((const float4*)x)[i];
        ushort4 o;
        o.x = f2bf(v.x); o.y = f2bf(v.y); o.z = f2bf(v.z); o.w = f2bf(v.w);
        ((ushort4*)x_bf)[i] = o;
        return;
    }
    const float* W;
    unsigned short* Wt;
    int tn, tk, N;
    if (bid < 8192 + 3072) {
        W = w_qkv; Wt = wqkvT; N = 3072;
        tn = (bid - 8192) % 96; tk = (bid - 8192) / 96;
    } else {
        W = w_out; Wt = woutT; N = 1024;
        tn = (bid - 11264) % 32; tk = (bid - 11264) / 32;
    }
    const int K = 1024;
    int lx = threadIdx.x & 31, ly = threadIdx.x >> 5;  // 32 x 8
    #pragma unroll
    for (int i = 0; i < 32; i += 8) {
        int k = tk * 32 + ly + i;
        int n = tn * 32 + lx;
        tile[ly + i][lx] = f2bf(W[(size_t)k * N + n]);
    }
    __syncthreads();
    int k2 = tk * 32 + lx;
    #pragma unroll
    for (int i = 0; i < 32; i += 8) {
        int n2 = tn * 32 + ly + i;
        Wt[(size_t)n2 * K + k2] = tile[lx][ly + i];
    }
}

// --------- C[M][N] = A[M][K] * Bt[N][K]^T   (bf16 in) -----------------------
// BK=64 + row&7 XOR LDS swizzle (both-sides; verified R11).
// MODE 0: plain fp32 C. MODE 1: fused QKV epilogue (Q*0.125*log2e|K -> qk,
// V -> vt transposed; strides QKP).
template<int MODE>
__global__ __launch_bounds__(256) void k_gemm_bt(const unsigned short* __restrict__ A,
                                                 const unsigned short* __restrict__ Bt,
                                                 void* __restrict__ Cv,
                                                 unsigned short* __restrict__ vtv,
                                                 int M, int N_, int K) {
    constexpr int BM = 128, BN = 128, BK = 64;
    __shared__ unsigned short lA[BM * BK];
    __shared__ unsigned short lB[BN * BK];
    const int ntile = N_ / BN;
    const int tm = blockIdx.x / ntile;
    const int tn = blockIdx.x % ntile;
    const int t = threadIdx.x;
    const int w = t >> 6, l = t & 63;
    const int wr = w >> 1, wc = w & 1;

    const unsigned short* Abase = A + (size_t)tm * BM * K;
    const unsigned short* Bbase = Bt + (size_t)tn * BN * K;

    f32x4 acc[4][4] = {};

    const int rswz = (l & 7) << 4;

    for (int k0 = 0; k0 < K; k0 += BK) {
        __syncthreads();
        #pragma unroll
        for (int i = 0; i < 4; ++i) {
            const int o  = i * 4096 + t * 16;
            const int so = o ^ (((o >> 7) & 7) << 4);
            const int row = so >> 7;
            const int kb  = so & 127;
            gload_lds16((const char*)(Abase + (size_t)row * K + k0) + kb,
                        (char*)lA + i * 4096 + w * 1024);
            gload_lds16((const char*)(Bbase + (size_t)row * K + k0) + kb,
                        (char*)lB + i * 4096 + w * 1024);
        }
        __syncthreads();

        #pragma unroll
        for (int kk = 0; kk < 2; ++kk) {
            bf16x8 af[4], bfv[4];
            #pragma unroll
            for (int i = 0; i < 4; ++i) {
                const int ea = ((wr * 64 + i * 16 + (l & 15)) << 7) + kk * 64 + ((l >> 4) << 4);
                af[i] = *(const bf16x8*)((const char*)lA + (ea ^ rswz));
            }
            #pragma unroll
            for (int j = 0; j < 4; ++j) {
                const int eb = ((wc * 64 + j * 16 + (l & 15)) << 7) + kk * 64 + ((l >> 4) << 4);
                bfv[j] = *(const bf16x8*)((const char*)lB + (eb ^ rswz));
            }
            #pragma unroll
            for (int i = 0; i < 4; ++i)
                #pragma unroll
                for (int j = 0; j < 4; ++j)
                    acc[i][j] = __builtin_amdgcn_mfma_f32_16x16x32_bf16(af[i], bfv[j], acc[i][j], 0, 0, 0);
        }
    }

    const int row0 = tm * BM + wr * 64 + (l >> 4) * 4;
    const int col0 = tn * BN + wc * 64 + (l & 15);

    if (MODE == 0) {
        float* Cf = (float*)Cv;
        #pragma unroll
        for (int i = 0; i < 4; ++i)
            #pragma unroll
            for (int j = 0; j < 4; ++j)
                #pragma unroll
                for (int r = 0; r < 4; ++r)
                    Cf[(size_t)(row0 + i * 16 + r) * N_ + (col0 + j * 16)] = acc[i][j][r];
    } else if (tn < 16) {
        const float cs = (tn < 8) ? 0.125f * LOG2E : 1.0f;
        unsigned short* qk = (unsigned short*)Cv;
        #pragma unroll
        for (int i = 0; i < 4; ++i)
            #pragma unroll
            for (int j = 0; j < 4; ++j)
                #pragma unroll
                for (int r = 0; r < 4; ++r)
                    qk[(size_t)(row0 + i * 16 + r) * QKP + (col0 + j * 16)] = f2bf(acc[i][j][r] * cs);
    } else {
        #pragma unroll
        for (int i = 0; i < 4; ++i) {
            const int rbase = row0 + i * 16;
            const int bq = rbase >> 11;
            const int n0 = rbase & 2047;
            #pragma unroll
            for (int j = 0; j < 4; ++j) {
                const int c = col0 + j * 16 - 2048;
                const int hh = c >> 6, dd = c & 63;
                uint2 u;
                u.x = (unsigned int)f2bf(acc[i][j][0]) | ((unsigned int)f2bf(acc[i][j][1]) << 16);
                u.y = (unsigned int)f2bf(acc[i][j][2]) | ((unsigned int)f2bf(acc[i][j][3]) << 16);
                *(uint2*)(vtv + ((size_t)(bq * 16 + hh) * 64 + dd) * QKP + n0) = u;
            }
        }
    }
}

// -- causal flash attention (v19: R18 + compile-time mask split) -------------
// Mask (v_cmp+cndmask x64/tile) was executed EVERY tile although only the
// diagonal tile needs it (~20% of tile VALU). Split: unmasked body for
// kt < nt-1, masked body once. Body otherwise identical to R16/R18.
__global__ __launch_bounds__(64, 2) void k_attn19(const unsigned short* __restrict__ qk,
                                                  const unsigned short* __restrict__ vt,
                                                  unsigned short* __restrict__ out) {
    const int bid = blockIdx.x;               // 4096
    const int bh = bid & 63;                  // same-bh blocks stride-8 -> XCD-local
    const int c32 = 63 - (bid >> 6);          // heavy chunks first
    const int b = bh >> 4, h = bh & 15;
    const int l = threadIdx.x;                // 0..63
    const int l31 = l & 31, hi = l >> 5;

    const unsigned short* qp = qk + (size_t)(b * SEQ) * QKP + h * 64;   // Q cols
    unsigned short* op = out + (size_t)(b * SEQ) * DIMM + h * 64;

    constexpr int KSTEP = 64 * QKP * 2;       // 64 kv rows in qk (bytes)
    constexpr int VSTEP = 64 * 2;             // 64 kv cols in vt (bytes)

    union U8 { uint32_t u[4]; bf16x8 v; };

    const int q0w = c32 * 32;                 // wave's first q row
    const int qrow = q0w + l31;               // this lane's q row
    const int nt = (q0w >> 6) + 1;            // kv-tile trip count

    // Q as B-operand: col = l31 (q), k = m*16 + hi*8 + e (prescaled 1/8*log2e)
    bf16x8 qf[4];
    #pragma unroll
    for (int m = 0; m < 4; ++m)
        qf[m] = *(const bf16x8*)(qp + (size_t)(q0w + l31) * QKP + m * 16 + hi * 8);

    // O^T accumulators: rows d = crow(r,hi) / 32+crow, col q = l31 (own lane)
    f32x16 accO0 = {}, accO1 = {};
    float m_run = -INFINITY, l_run = 0.f;

    // incremental byte pointers (K rows kv = {0,32}+l31; V^T rows d = {0,32}+l31)
    const char* kp0 = (const char*)(qk + ((size_t)b * SEQ + l31) * QKP + 1024 + h * 64 + hi * 8);
    const char* kp1 = kp0 + 32 * QKP * 2;
    const char* vp0 = (const char*)(vt + ((size_t)bh * 64 + l31) * QKP + hi * 8);
    const char* vp1 = vp0 + 32 * QKP * 2;

    // K tile 0 into registers; pointers advance to tile 1
    bf16x8 kf[2][4];
    #pragma unroll
    for (int m = 0; m < 4; ++m) {
        kf[0][m] = *(const bf16x8*)(kp0 + m * 32);
        kf[1][m] = *(const bf16x8*)(kp1 + m * 32);
    }
    kp0 += KSTEP; kp1 += KSTEP;

    // one kv-tile; MSK is compile-time
    auto tile = [&](int kv0, auto mskc) {
        constexpr bool MSK = decltype(mskc)::value;

        // QK^T swapped -> S^T: lane holds q=l31, kv = f*32 + crow(r,hi)
        f32x16 s0 = {}, s1 = {};
        __builtin_amdgcn_s_setprio(1);
        #pragma unroll
        for (int m = 0; m < 4; ++m) {
            s0 = __builtin_amdgcn_mfma_f32_32x32x16_bf16(kf[0][m], qf[m], s0, 0, 0, 0);
            s1 = __builtin_amdgcn_mfma_f32_32x32x16_bf16(kf[1][m], qf[m], s1, 0, 0, 0);
        }
        __builtin_amdgcn_s_setprio(0);

        // V^T fragments for current tile (imm offsets), issued early
        bf16x8 vf0[4], vf1[4];
        #pragma unroll
        for (int m = 0; m < 4; ++m) {
            vf0[m] = *(const bf16x8*)(vp0 + m * 32);
            vf1[m] = *(const bf16x8*)(vp1 + m * 32);
        }
        vp0 += VSTEP; vp1 += VSTEP;

        // K prefetch for next tile (unconditional; overrun is valid ws)
        #pragma unroll
        for (int m = 0; m < 4; ++m) {
            kf[0][m] = *(const bf16x8*)(kp0 + m * 32);
            kf[1][m] = *(const bf16x8*)(kp1 + m * 32);
        }
        kp0 += KSTEP; kp1 += KSTEP;

        // ---- in-lane online softmax, exp2 domain, T13 defer-max ----
        float tmax = -1e30f;
        #pragma unroll
        for (int r = 0; r < 16; ++r) {
            float v0 = s0[r];
            float v1 = s1[r];
            if (MSK) {
                const int crow = (r & 3) + 8 * (r >> 2) + 4 * hi;
                if (kv0 + crow > qrow)      v0 = -1e30f;
                if (kv0 + 32 + crow > qrow) v1 = -1e30f;
                s0[r] = v0; s1[r] = v1;
            }
            tmax = fmaxf(tmax, fmaxf(v0, v1));
        }
        tmax = fmaxf(tmax, __shfl_xor(tmax, 32));      // other kv half
        const bool defer = __all(tmax <= m_run + 8.0f);  // P bounded by 2^8
        float fct = 1.0f;
        if (!defer) {
            const float mnew = fmaxf(m_run, tmax);
            fct = exp2f(m_run - mnew);
            m_run = mnew;
            #pragma unroll
            for (int r = 0; r < 16; ++r) { accO0[r] *= fct; accO1[r] *= fct; }
        }
        float ps = 0.f;
        #pragma unroll
        for (int r = 0; r < 16; ++r) {
            float p0 = exp2f(s0[r] - m_run);
            float p1 = exp2f(s1[r] - m_run);
            s0[r] = p0; s1[r] = p1;
            ps += p0 + p1;
        }
        ps += __shfl_xor(ps, 32);
        l_run = l_run * fct + ps;

        // ---- P -> bf16 pack + permlane redistribution + PV (O^T) ----
        uint32_t pw0[8], pw1[8];
        #pragma unroll
        for (int i = 0; i < 8; ++i) {
            asm("v_cvt_pk_bf16_f32 %0, %1, %2" : "=v"(pw0[i]) : "v"(s0[2*i]), "v"(s0[2*i+1]));
            asm("v_cvt_pk_bf16_f32 %0, %1, %2" : "=v"(pw1[i]) : "v"(s1[2*i]), "v"(s1[2*i+1]));
        }
        __builtin_amdgcn_s_setprio(1);
        #define PVCHUNK(PW, BASE, VF0, VF1) do {                                     \
            uint32_t a0 = PW[BASE+0], b0 = PW[BASE+2];                               \
            uint32_t a1 = PW[BASE+1], b1 = PW[BASE+3];                               \
            asm("v_permlane32_swap_b32 %0, %1" : "+v"(a0), "+v"(b0));                \
            asm("v_permlane32_swap_b32 %0, %1" : "+v"(a1), "+v"(b1));                \
            U8 pb; pb.u[0] = a0; pb.u[1] = a1; pb.u[2] = b0; pb.u[3] = b1;           \
            accO0 = __builtin_amdgcn_mfma_f32_32x32x16_bf16(VF0, pb.v, accO0, 0, 0, 0); \
            accO1 = __builtin_amdgcn_mfma_f32_32x32x16_bf16(VF1, pb.v, accO1, 0, 0, 0); \
        } while (0)
        PVCHUNK(pw0, 0, vf0[0], vf1[0]);
        PVCHUNK(pw0, 4, vf0[1], vf1[1]);
        PVCHUNK(pw1, 0, vf0[2], vf1[2]);
        PVCHUNK(pw1, 4, vf0[3], vf1[3]);
        #undef PVCHUNK
        __builtin_amdgcn_s_setprio(0);
    };

    for (int kt = 0; kt + 1 < nt; ++kt) tile(kt * 64, BoolC<false>{});
    tile((nt - 1) * 64, BoolC<true>{});

    // epilogue: lane holds O[q = q0w+l31][d = crow + {0,32}], own l_run.
    const float inv = 1.0f / l_run;
    unsigned short* orow = op + (size_t)(q0w + l31) * DIMM;
    #pragma unroll
    for (int g = 0; g < 4; ++g) {
        uint2 u0, u1;
        float a0 = accO0[4*g+0] * inv, a1 = accO0[4*g+1] * inv;
        float a2 = accO0[4*g+2] * inv, a3 = accO0[4*g+3] * inv;
        float c0 = accO1[4*g+0] * inv, c1 = accO1[4*g+1] * inv;
        float c2 = accO1[4*g+2] * inv, c3 = accO1[4*g+3] * inv;
        asm("v_cvt_pk_bf16_f32 %0, %1, %2" : "=v"(u0.x) : "v"(a0), "v"(a1));
        asm("v_cvt_pk_bf16_f32 %0, %1, %2" : "=v"(u0.y) : "v"(a2), "v"(a3));
        asm("v_cvt_pk_bf16_f32 %0, %1, %2" : "=v"(u1.x) : "v"(c0), "v"(c1));
        asm("v_cvt_pk_bf16_f32 %0, %1, %2" : "=v"(u1.y) : "v"(c2), "v"(c3));
        *(uint2*)(orow + 8*g + 4*hi)      = u0;   // d = 8g+4hi .. +3
        *(uint2*)(orow + 32 + 8*g + 4*hi) = u1;   // d = 32+8g+4hi .. +3
    }
}

// ---------------------------------------------------------------------------
extern "C" void kernel_launch(void* const* d_in, const int* in_sizes, int n_in,
                              void* d_out, int out_size, void* d_ws, size_t ws_size,
                              hipStream_t stream) {
    const float* x     = (const float*)d_in[0];   // [4,2048,1024]
    const float* w_qkv = (const float*)d_in[1];   // [1024,3072]
    const float* w_out = (const float*)d_in[2];   // [1024,1024]

    unsigned short* x_bf   = (unsigned short*)d_ws;
    unsigned short* wqkvT  = x_bf   + (size_t)MROWS * DIMM;
    unsigned short* woutT  = wqkvT  + (size_t)3 * DIMM * DIMM;
    unsigned short* qk_buf = woutT  + (size_t)DIMM * DIMM;           // [8192][QKP]
    unsigned short* vt     = qk_buf + (size_t)MROWS * QKP;           // [64][64][QKP]
    unsigned short* aout   = vt     + (size_t)64 * DH * QKP;         // [8192][1024]

    // 1. fused prep: conv + both weight transposes in one dispatch
    k_prep<<<8192 + 3072 + 1024, 256, 0, stream>>>(x, x_bf, w_qkv, wqkvT, w_out, woutT);

    // 2. QKV projection, fused epilogue: Q(scaled)|K -> qk_buf, V^T -> vt
    k_gemm_bt<1><<<(MROWS / 128) * (3 * DIMM / 128), 256, 0, stream>>>(
        x_bf, wqkvT, qk_buf, vt, MROWS, 3 * DIMM, DIMM);

    // 3. causal flash attention (compile-time mask split)
    k_attn19<<<4096, 64, 0, stream>>>(qk_buf, vt, aout);

    // 4. output projection: [8192,1024] x [1024,1024] -> fp32 d_out
    k_gemm_bt<0><<<(MROWS / 128) * (DIMM / 128), 256, 0, stream>>>(
        aout, woutT, d_out, nullptr, MROWS, DIMM, DIMM);
}

// Round 20
// 198.118 us; speedup vs baseline: 1.8156x; 1.0050x over previous
//
#include <hip/hip_runtime.h>
#include <hip/hip_bf16.h>
#include <stdint.h>

// Problem constants
#define SEQ  2048
#define DIMM 1024
#define NH   16
#define DH   64
#define NB   4
#define MROWS (NB*SEQ)   // 8192
#define QKP  2080        // padded row stride for qk/vt (breaks 4KB aliasing)

typedef __attribute__((ext_vector_type(8))) short bf16x8;
typedef __attribute__((ext_vector_type(4))) float f32x4;
typedef __attribute__((ext_vector_type(16))) float f32x16;

#define LOG2E 1.44269504088896340736f

template<bool B> struct BoolC { static constexpr bool value = B; };

__device__ __forceinline__ unsigned short f2bf(float f) {
    union { float f; uint32_t u; } c; c.f = f;
    uint32_t r = c.u + 0x7fff + ((c.u >> 16) & 1);
    return (unsigned short)(r >> 16);
}

__device__ __forceinline__ void gload_lds16(const void* g, void* lds) {
    __builtin_amdgcn_global_load_lds(
        (const __attribute__((address_space(1))) unsigned int*)(g),
        (__attribute__((address_space(3))) unsigned int*)(lds),
        16, 0, 0);
}

// ---- fused prep: x fp32->bf16 convert + both weight transposes ------------
__global__ __launch_bounds__(256) void k_prep(const float* __restrict__ x,
                                              unsigned short* __restrict__ x_bf,
                                              const float* __restrict__ w_qkv,
                                              unsigned short* __restrict__ wqkvT,
                                              const float* __restrict__ w_out,
                                              unsigned short* __restrict__ woutT) {
    __shared__ unsigned short tile[32][33];
    const int bid = blockIdx.x;
    if (bid < 8192) {
        int i = bid * 256 + threadIdx.x;
        float4 v = ((const float4*)x)[i];
        ushort4 o;
        o.x = f2bf(v.x); o.y = f2bf(v.y); o.z = f2bf(v.z); o.w = f2bf(v.w);
        ((ushort4*)x_bf)[i] = o;
        return;
    }
    const float* W;
    unsigned short* Wt;
    int tn, tk, N;
    if (bid < 8192 + 3072) {
        W = w_qkv; Wt = wqkvT; N = 3072;
        tn = (bid - 8192) % 96; tk = (bid - 8192) / 96;
    } else {
        W = w_out; Wt = woutT; N = 1024;
        tn = (bid - 11264) % 32; tk = (bid - 11264) / 32;
    }
    const int K = 1024;
    int lx = threadIdx.x & 31, ly = threadIdx.x >> 5;  // 32 x 8
    #pragma unroll
    for (int i = 0; i < 32; i += 8) {
        int k = tk * 32 + ly + i;
        int n = tn * 32 + lx;
        tile[ly + i][lx] = f2bf(W[(size_t)k * N + n]);
    }
    __syncthreads();
    int k2 = tk * 32 + lx;
    #pragma unroll
    for (int i = 0; i < 32; i += 8) {
        int n2 = tn * 32 + ly + i;
        Wt[(size_t)n2 * K + k2] = tile[lx][ly + i];
    }
}

// --------- C[M][N] = A[M][K] * Bt[N][K]^T   (bf16 in) -----------------------
// BK=64 + row&7 XOR LDS swizzle (both-sides; verified R11) + bijective XCD
// block swizzle (each XCD works a contiguous tm range -> A panels L2-local).
// MODE 0: plain fp32 C. MODE 1: fused QKV epilogue (Q*0.125*log2e|K -> qk,
// V -> vt transposed; strides QKP).
template<int MODE>
__global__ __launch_bounds__(256) void k_gemm_bt(const unsigned short* __restrict__ A,
                                                 const unsigned short* __restrict__ Bt,
                                                 void* __restrict__ Cv,
                                                 unsigned short* __restrict__ vtv,
                                                 int M, int N_, int K) {
    constexpr int BM = 128, BN = 128, BK = 64;
    __shared__ unsigned short lA[BM * BK];
    __shared__ unsigned short lB[BN * BK];
    const int ntile = N_ / BN;
    // bijective XCD swizzle: gridDim.x divisible by 8 (1536 / 512)
    const int wgid = (blockIdx.x & 7) * (gridDim.x >> 3) + (blockIdx.x >> 3);
    const int tm = wgid / ntile;
    const int tn = wgid % ntile;
    const int t = threadIdx.x;
    const int w = t >> 6, l = t & 63;
    const int wr = w >> 1, wc = w & 1;

    const unsigned short* Abase = A + (size_t)tm * BM * K;
    const unsigned short* Bbase = Bt + (size_t)tn * BN * K;

    f32x4 acc[4][4] = {};

    const int rswz = (l & 7) << 4;

    for (int k0 = 0; k0 < K; k0 += BK) {
        __syncthreads();
        #pragma unroll
        for (int i = 0; i < 4; ++i) {
            const int o  = i * 4096 + t * 16;
            const int so = o ^ (((o >> 7) & 7) << 4);
            const int row = so >> 7;
            const int kb  = so & 127;
            gload_lds16((const char*)(Abase + (size_t)row * K + k0) + kb,
                        (char*)lA + i * 4096 + w * 1024);
            gload_lds16((const char*)(Bbase + (size_t)row * K + k0) + kb,
                        (char*)lB + i * 4096 + w * 1024);
        }
        __syncthreads();

        #pragma unroll
        for (int kk = 0; kk < 2; ++kk) {
            bf16x8 af[4], bfv[4];
            #pragma unroll
            for (int i = 0; i < 4; ++i) {
                const int ea = ((wr * 64 + i * 16 + (l & 15)) << 7) + kk * 64 + ((l >> 4) << 4);
                af[i] = *(const bf16x8*)((const char*)lA + (ea ^ rswz));
            }
            #pragma unroll
            for (int j = 0; j < 4; ++j) {
                const int eb = ((wc * 64 + j * 16 + (l & 15)) << 7) + kk * 64 + ((l >> 4) << 4);
                bfv[j] = *(const bf16x8*)((const char*)lB + (eb ^ rswz));
            }
            #pragma unroll
            for (int i = 0; i < 4; ++i)
                #pragma unroll
                for (int j = 0; j < 4; ++j)
                    acc[i][j] = __builtin_amdgcn_mfma_f32_16x16x32_bf16(af[i], bfv[j], acc[i][j], 0, 0, 0);
        }
    }

    const int row0 = tm * BM + wr * 64 + (l >> 4) * 4;
    const int col0 = tn * BN + wc * 64 + (l & 15);

    if (MODE == 0) {
        float* Cf = (float*)Cv;
        #pragma unroll
        for (int i = 0; i < 4; ++i)
            #pragma unroll
            for (int j = 0; j < 4; ++j)
                #pragma unroll
                for (int r = 0; r < 4; ++r)
                    Cf[(size_t)(row0 + i * 16 + r) * N_ + (col0 + j * 16)] = acc[i][j][r];
    } else if (tn < 16) {
        const float cs = (tn < 8) ? 0.125f * LOG2E : 1.0f;
        unsigned short* qk = (unsigned short*)Cv;
        #pragma unroll
        for (int i = 0; i < 4; ++i)
            #pragma unroll
            for (int j = 0; j < 4; ++j)
                #pragma unroll
                for (int r = 0; r < 4; ++r)
                    qk[(size_t)(row0 + i * 16 + r) * QKP + (col0 + j * 16)] = f2bf(acc[i][j][r] * cs);
    } else {
        #pragma unroll
        for (int i = 0; i < 4; ++i) {
            const int rbase = row0 + i * 16;
            const int bq = rbase >> 11;
            const int n0 = rbase & 2047;
            #pragma unroll
            for (int j = 0; j < 4; ++j) {
                const int c = col0 + j * 16 - 2048;
                const int hh = c >> 6, dd = c & 63;
                uint2 u;
                u.x = (unsigned int)f2bf(acc[i][j][0]) | ((unsigned int)f2bf(acc[i][j][1]) << 16);
                u.y = (unsigned int)f2bf(acc[i][j][2]) | ((unsigned int)f2bf(acc[i][j][3]) << 16);
                *(uint2*)(vtv + ((size_t)(bq * 16 + hh) * 64 + dd) * QKP + n0) = u;
            }
        }
    }
}

// -- causal flash attention (v20: R19 body, 4-wave blocks x 4 blocks/CU) -----
// Residency evidence (R16/R18/R19): ~6 waves/CU regardless of supply shape;
// 1-wave workgroups appear slot-limited. Supply 16 waves/CU as 1024 x 4-wave
// blocks: wave w of block g owns chunk c32 = 63-(4g+w) (heavy-first; all
// 64x64 (bh,chunk) covered once). Body identical to R19 (mask split etc).
__global__ __launch_bounds__(256, 2) void k_attn20(const unsigned short* __restrict__ qk,
                                                   const unsigned short* __restrict__ vt,
                                                   unsigned short* __restrict__ out) {
    const int bid = blockIdx.x;               // 1024
    const int bh = bid & 63;                  // XCD x gets 8 distinct bh
    const int w = threadIdx.x >> 6;           // wave 0..3
    const int c32 = 63 - ((bid >> 6) * 4 + w);// heavy chunks first
    const int b = bh >> 4, h = bh & 15;
    const int l = threadIdx.x & 63;
    const int l31 = l & 31, hi = l >> 5;

    const unsigned short* qp = qk + (size_t)(b * SEQ) * QKP + h * 64;   // Q cols
    unsigned short* op = out + (size_t)(b * SEQ) * DIMM + h * 64;

    constexpr int KSTEP = 64 * QKP * 2;       // 64 kv rows in qk (bytes)
    constexpr int VSTEP = 64 * 2;             // 64 kv cols in vt (bytes)

    union U8 { uint32_t u[4]; bf16x8 v; };

    const int q0w = c32 * 32;                 // wave's first q row
    const int qrow = q0w + l31;               // this lane's q row
    const int nt = (q0w >> 6) + 1;            // kv-tile trip count

    // Q as B-operand: col = l31 (q), k = m*16 + hi*8 + e (prescaled 1/8*log2e)
    bf16x8 qf[4];
    #pragma unroll
    for (int m = 0; m < 4; ++m)
        qf[m] = *(const bf16x8*)(qp + (size_t)(q0w + l31) * QKP + m * 16 + hi * 8);

    // O^T accumulators: rows d = crow(r,hi) / 32+crow, col q = l31 (own lane)
    f32x16 accO0 = {}, accO1 = {};
    float m_run = -INFINITY, l_run = 0.f;

    // incremental byte pointers (K rows kv = {0,32}+l31; V^T rows d = {0,32}+l31)
    const char* kp0 = (const char*)(qk + ((size_t)b * SEQ + l31) * QKP + 1024 + h * 64 + hi * 8);
    const char* kp1 = kp0 + 32 * QKP * 2;
    const char* vp0 = (const char*)(vt + ((size_t)bh * 64 + l31) * QKP + hi * 8);
    const char* vp1 = vp0 + 32 * QKP * 2;

    // K tile 0 into registers; pointers advance to tile 1
    bf16x8 kf[2][4];
    #pragma unroll
    for (int m = 0; m < 4; ++m) {
        kf[0][m] = *(const bf16x8*)(kp0 + m * 32);
        kf[1][m] = *(const bf16x8*)(kp1 + m * 32);
    }
    kp0 += KSTEP; kp1 += KSTEP;

    // one kv-tile; MSK is compile-time
    auto tile = [&](int kv0, auto mskc) {
        constexpr bool MSK = decltype(mskc)::value;

        // QK^T swapped -> S^T: lane holds q=l31, kv = f*32 + crow(r,hi)
        f32x16 s0 = {}, s1 = {};
        __builtin_amdgcn_s_setprio(1);
        #pragma unroll
        for (int m = 0; m < 4; ++m) {
            s0 = __builtin_amdgcn_mfma_f32_32x32x16_bf16(kf[0][m], qf[m], s0, 0, 0, 0);
            s1 = __builtin_amdgcn_mfma_f32_32x32x16_bf16(kf[1][m], qf[m], s1, 0, 0, 0);
        }
        __builtin_amdgcn_s_setprio(0);

        // V^T fragments for current tile (imm offsets), issued early
        bf16x8 vf0[4], vf1[4];
        #pragma unroll
        for (int m = 0; m < 4; ++m) {
            vf0[m] = *(const bf16x8*)(vp0 + m * 32);
            vf1[m] = *(const bf16x8*)(vp1 + m * 32);
        }
        vp0 += VSTEP; vp1 += VSTEP;

        // K prefetch for next tile (unconditional; overrun is valid ws)
        #pragma unroll
        for (int m = 0; m < 4; ++m) {
            kf[0][m] = *(const bf16x8*)(kp0 + m * 32);
            kf[1][m] = *(const bf16x8*)(kp1 + m * 32);
        }
        kp0 += KSTEP; kp1 += KSTEP;

        // ---- in-lane online softmax, exp2 domain, T13 defer-max ----
        float tmax = -1e30f;
        #pragma unroll
        for (int r = 0; r < 16; ++r) {
            float v0 = s0[r];
            float v1 = s1[r];
            if (MSK) {
                const int crow = (r & 3) + 8 * (r >> 2) + 4 * hi;
                if (kv0 + crow > qrow)      v0 = -1e30f;
                if (kv0 + 32 + crow > qrow) v1 = -1e30f;
                s0[r] = v0; s1[r] = v1;
            }
            tmax = fmaxf(tmax, fmaxf(v0, v1));
        }
        tmax = fmaxf(tmax, __shfl_xor(tmax, 32));      // other kv half
        const bool defer = __all(tmax <= m_run + 8.0f);  // P bounded by 2^8
        float fct = 1.0f;
        if (!defer) {
            const float mnew = fmaxf(m_run, tmax);
            fct = exp2f(m_run - mnew);
            m_run = mnew;
            #pragma unroll
            for (int r = 0; r < 16; ++r) { accO0[r] *= fct; accO1[r] *= fct; }
        }
        float ps = 0.f;
        #pragma unroll
        for (int r = 0; r < 16; ++r) {
            float p0 = exp2f(s0[r] - m_run);
            float p1 = exp2f(s1[r] - m_run);
            s0[r] = p0; s1[r] = p1;
            ps += p0 + p1;
        }
        ps += __shfl_xor(ps, 32);
        l_run = l_run * fct + ps;

        // ---- P -> bf16 pack + permlane redistribution + PV (O^T) ----
        uint32_t pw0[8], pw1[8];
        #pragma unroll
        for (int i = 0; i < 8; ++i) {
            asm("v_cvt_pk_bf16_f32 %0, %1, %2" : "=v"(pw0[i]) : "v"(s0[2*i]), "v"(s0[2*i+1]));
            asm("v_cvt_pk_bf16_f32 %0, %1, %2" : "=v"(pw1[i]) : "v"(s1[2*i]), "v"(s1[2*i+1]));
        }
        __builtin_amdgcn_s_setprio(1);
        #define PVCHUNK(PW, BASE, VF0, VF1) do {                                     \
            uint32_t a0 = PW[BASE+0], b0 = PW[BASE+2];                               \
            uint32_t a1 = PW[BASE+1], b1 = PW[BASE+3];                               \
            asm("v_permlane32_swap_b32 %0, %1" : "+v"(a0), "+v"(b0));                \
            asm("v_permlane32_swap_b32 %0, %1" : "+v"(a1), "+v"(b1));                \
            U8 pb; pb.u[0] = a0; pb.u[1] = a1; pb.u[2] = b0; pb.u[3] = b1;           \
            accO0 = __builtin_amdgcn_mfma_f32_32x32x16_bf16(VF0, pb.v, accO0, 0, 0, 0); \
            accO1 = __builtin_amdgcn_mfma_f32_32x32x16_bf16(VF1, pb.v, accO1, 0, 0, 0); \
        } while (0)
        PVCHUNK(pw0, 0, vf0[0], vf1[0]);
        PVCHUNK(pw0, 4, vf0[1], vf1[1]);
        PVCHUNK(pw1, 0, vf0[2], vf1[2]);
        PVCHUNK(pw1, 4, vf0[3], vf1[3]);
        #undef PVCHUNK
        __builtin_amdgcn_s_setprio(0);
    };

    for (int kt = 0; kt + 1 < nt; ++kt) tile(kt * 64, BoolC<false>{});
    tile((nt - 1) * 64, BoolC<true>{});

    // epilogue: lane holds O[q = q0w+l31][d = crow + {0,32}], own l_run.
    const float inv = 1.0f / l_run;
    unsigned short* orow = op + (size_t)(q0w + l31) * DIMM;
    #pragma unroll
    for (int g = 0; g < 4; ++g) {
        uint2 u0, u1;
        float a0 = accO0[4*g+0] * inv, a1 = accO0[4*g+1] * inv;
        float a2 = accO0[4*g+2] * inv, a3 = accO0[4*g+3] * inv;
        float c0 = accO1[4*g+0] * inv, c1 = accO1[4*g+1] * inv;
        float c2 = accO1[4*g+2] * inv, c3 = accO1[4*g+3] * inv;
        asm("v_cvt_pk_bf16_f32 %0, %1, %2" : "=v"(u0.x) : "v"(a0), "v"(a1));
        asm("v_cvt_pk_bf16_f32 %0, %1, %2" : "=v"(u0.y) : "v"(a2), "v"(a3));
        asm("v_cvt_pk_bf16_f32 %0, %1, %2" : "=v"(u1.x) : "v"(c0), "v"(c1));
        asm("v_cvt_pk_bf16_f32 %0, %1, %2" : "=v"(u1.y) : "v"(c2), "v"(c3));
        *(uint2*)(orow + 8*g + 4*hi)      = u0;   // d = 8g+4hi .. +3
        *(uint2*)(orow + 32 + 8*g + 4*hi) = u1;   // d = 32+8g+4hi .. +3
    }
}

// ---------------------------------------------------------------------------
extern "C" void kernel_launch(void* const* d_in, const int* in_sizes, int n_in,
                              void* d_out, int out_size, void* d_ws, size_t ws_size,
                              hipStream_t stream) {
    const float* x     = (const float*)d_in[0];   // [4,2048,1024]
    const float* w_qkv = (const float*)d_in[1];   // [1024,3072]
    const float* w_out = (const float*)d_in[2];   // [1024,1024]

    unsigned short* x_bf   = (unsigned short*)d_ws;
    unsigned short* wqkvT  = x_bf   + (size_t)MROWS * DIMM;
    unsigned short* woutT  = wqkvT  + (size_t)3 * DIMM * DIMM;
    unsigned short* qk_buf = woutT  + (size_t)DIMM * DIMM;           // [8192][QKP]
    unsigned short* vt     = qk_buf + (size_t)MROWS * QKP;           // [64][64][QKP]
    unsigned short* aout   = vt     + (size_t)64 * DH * QKP;         // [8192][1024]

    // 1. fused prep: conv + both weight transposes in one dispatch
    k_prep<<<8192 + 3072 + 1024, 256, 0, stream>>>(x, x_bf, w_qkv, wqkvT, w_out, woutT);

    // 2. QKV projection, fused epilogue: Q(scaled)|K -> qk_buf, V^T -> vt
    k_gemm_bt<1><<<(MROWS / 128) * (3 * DIMM / 128), 256, 0, stream>>>(
        x_bf, wqkvT, qk_buf, vt, MROWS, 3 * DIMM, DIMM);

    // 3. causal flash attention (4-wave blocks, 16 waves/CU supply)
    k_attn20<<<1024, 256, 0, stream>>>(qk_buf, vt, aout);

    // 4. output projection: [8192,1024] x [1024,1024] -> fp32 d_out
    k_gemm_bt<0><<<(MROWS / 128) * (DIMM / 128), 256, 0, stream>>>(
        aout, woutT, d_out, nullptr, MROWS, DIMM, DIMM);
}